// Round 13
// baseline (184.706 us; speedup 1.0000x reference)
//
#include <hip/hip_runtime.h>

#define B_ 128
#define E_ 16
#define S_ 32768

constexpr int BLK = 256;                // threads per block
constexpr int CH  = 2048;               // positions per chunk
constexpr int NCH = S_ / (2 * CH);      // 8 blocks per row (fwd + mirror chunk)
// 8 x 128 = 1024 blocks; at <=128 VGPR (launch_bounds cap) all 1024 are
// co-resident (4 blocks/CU x 256 CU) -> the per-row spin barrier is safe.

// Gather-accumulate one float4 into FOUR NAMED SCALAR floats (no float4 acc:
// scalars survive the barrier CFG; float4 HIP_vector_type kept demoting).
#define GATHER4(A0, A1, A2, A3, P)                                            \
    {                                                                         \
        const int s_  = (P) - off;                                            \
        const int sc_ = s_ < 0 ? 0 : s_;        /* clamped: always in-bounds */\
        float4 v_ = *reinterpret_cast<const float4*>(rowbase + sc_);          \
        const float mk_ = s_ >= 0 ? 1.0f : 0.0f;                              \
        A0 = fmaf(v_.x, mk_, A0);                                             \
        A1 = fmaf(v_.y, mk_, A1);                                             \
        A2 = fmaf(v_.z, mk_, A2);                                             \
        A3 = fmaf(v_.w, mk_, A3);                                             \
        if (s_ > -4 && s_ < 0) {                /* straddle: 1 lane per (b,e) */\
            A3 += rowbase[(P) + 3 - off];       /* s_>=-3 => +3 valid */      \
            if (s_ >= -2) A2 += rowbase[(P) + 2 - off];                       \
            if (s_ >= -1) A1 += rowbase[(P) + 1 - off];                       \
        }                                                                     \
    }

#define PIN16()                                                               \
    asm volatile("" : "+v"(a00), "+v"(a01), "+v"(a02), "+v"(a03),             \
                      "+v"(a10), "+v"(a11), "+v"(a12), "+v"(a13),             \
                      "+v"(a20), "+v"(a21), "+v"(a22), "+v"(a23),             \
                      "+v"(a30), "+v"(a31), "+v"(a32), "+v"(a33))

__global__ __launch_bounds__(BLK, 4) void fused_scatter_norm(
    const float* __restrict__ events, const int* __restrict__ indices,
    float* __restrict__ out, float* __restrict__ pmax, unsigned* __restrict__ cnt)
{
    const int b  = blockIdx.y;
    const int cx = blockIdx.x;
    const int t  = (int)threadIdx.x;

    // Reflection pairing (R7): fwd chunk [cx*2048,+2048), mirror chunk
    // [S-2048*(cx+1),+2048) -> expected work ~constant in cx.
    const int pF = cx * CH + 4 * t;               // a0x.. @ pF, a1x.. @ pF+1024
    const int pM = (S_ - CH * (cx + 1)) + 4 * t;  // a2x.. @ pM, a3x.. @ pM+1024

    float a00 = 0.f, a01 = 0.f, a02 = 0.f, a03 = 0.f;
    float a10 = 0.f, a11 = 0.f, a12 = 0.f, a13 = 0.f;
    float a20 = 0.f, a21 = 0.f, a22 = 0.f, a23 = 0.f;
    float a30 = 0.f, a31 = 0.f, a32 = 0.f, a33 = 0.f;

    const float* evb  = events + (size_t)b * (E_ * S_);
    const int*   idxb = indices + b * E_;

#pragma unroll 4
    for (int e = 0; e < E_; ++e) {
        const int off = idxb[e];                  // block-uniform scalar load
        const float* rowbase = evb + e * S_;      // events[b,e,0]
        GATHER4(a00, a01, a02, a03, pF)
        GATHER4(a10, a11, a12, a13, pF + 1024)
        GATHER4(a20, a21, a22, a23, pM)
        GATHER4(a30, a31, a32, a33, pM + 1024)
    }

    // ---- block max of the 16 per-thread sums ----
    float m = fmaxf(
        fmaxf(fmaxf(fmaxf(a00, a01), fmaxf(a02, a03)),
              fmaxf(fmaxf(a10, a11), fmaxf(a12, a13))),
        fmaxf(fmaxf(fmaxf(a20, a21), fmaxf(a22, a23)),
              fmaxf(fmaxf(a30, a31), fmaxf(a32, a33))));
#pragma unroll
    for (int d = 1; d < 64; d <<= 1)
        m = fmaxf(m, __shfl_xor(m, d, 64));

    __shared__ float wmax[BLK / 64];
    if ((t & 63) == 0) wmax[t >> 6] = m;
    __syncthreads();

    PIN16();   // force the 16 sums to live in VGPRs entering the barrier

    // publish block max + arrive (t==0 only), then ALL threads spin
    // (uniform CFG: no divergent branch wrapping the loop).
    if (t == 0) {
        float mm = fmaxf(fmaxf(wmax[0], wmax[1]), fmaxf(wmax[2], wmax[3]));
        __hip_atomic_store(&pmax[b * NCH + cx], mm,
                           __ATOMIC_RELEASE, __HIP_MEMORY_SCOPE_AGENT);
        __hip_atomic_fetch_add(&cnt[b], 1u,
                               __ATOMIC_ACQ_REL, __HIP_MEMORY_SCOPE_AGENT);
    }
    while (__hip_atomic_load(&cnt[b], __ATOMIC_ACQUIRE,
                             __HIP_MEMORY_SCOPE_AGENT) < (unsigned)NCH)
        __builtin_amdgcn_s_sleep(8);

    PIN16();   // and force them back in VGPRs on the way out

    // all threads redundantly reduce the 8 partials (same-address broadcast)
    float mr = -3.402823466e+38f;
#pragma unroll
    for (int c = 0; c < NCH; ++c)
        mr = fmaxf(mr, __hip_atomic_load(&pmax[b * NCH + c],
                                         __ATOMIC_RELAXED,
                                         __HIP_MEMORY_SCOPE_AGENT));
    const float inv = 1.0f / (mr + 1e-8f);

    // ---- normalize in-register, single output write ----
    float* ob = out + (size_t)b * S_;
    float4 o0 = {a00 * inv, a01 * inv, a02 * inv, a03 * inv};
    float4 o1 = {a10 * inv, a11 * inv, a12 * inv, a13 * inv};
    float4 o2 = {a20 * inv, a21 * inv, a22 * inv, a23 * inv};
    float4 o3 = {a30 * inv, a31 * inv, a32 * inv, a33 * inv};
    *reinterpret_cast<float4*>(ob + pF)        = o0;
    *reinterpret_cast<float4*>(ob + pF + 1024) = o1;
    *reinterpret_cast<float4*>(ob + pM)        = o2;
    *reinterpret_cast<float4*>(ob + pM + 1024) = o3;
}

extern "C" void kernel_launch(void* const* d_in, const int* in_sizes, int n_in,
                              void* d_out, int out_size, void* d_ws, size_t ws_size,
                              hipStream_t stream) {
    const float* events  = (const float*)d_in[0];
    const int*   indices = (const int*)d_in[1];
    float* out  = (float*)d_out;
    float*    pmax = (float*)d_ws;                    // B_*NCH floats = 4 KB
    unsigned* cnt  = (unsigned*)((char*)d_ws + B_ * NCH * sizeof(float));

    // barrier counters must be zero at every call (ws not re-poisoned)
    hipMemsetAsync(cnt, 0, B_ * sizeof(unsigned), stream);

    dim3 grid(NCH, B_);                 // 8 x 128 = 1024 blocks, normal launch
    fused_scatter_norm<<<grid, BLK, 0, stream>>>(events, indices, out, pmax, cnt);
}

// Round 14
// 34.694 us; speedup vs baseline: 5.3239x; 5.3239x over previous
//
#include <hip/hip_runtime.h>

#define B_ 128
#define E_ 16
#define S_ 32768

constexpr int BLK   = 256;              // threads per block (kernel A)
constexpr int HALF  = 1024;             // contiguous positions per sub-chunk
constexpr int NCH   = S_ / (2 * HALF);  // 16 blocks per row

typedef float f4v __attribute__((ext_vector_type(4)));   // builtin-compatible

// Unconditional clamped vector load + data-flow masking (R6). Straddle
// (partial vector) fixed by a rare scalar branch. Plain cached loads (R11
// showed nontemporal LOADS regress).
#define GATHER(A, P)                                                          \
    {                                                                         \
        const int s_  = (P) - off;                                            \
        const int sc_ = s_ < 0 ? 0 : s_;        /* clamped: always in-bounds */\
        float4 v_ = *reinterpret_cast<const float4*>(rowbase + sc_);          \
        const float mk_ = s_ >= 0 ? 1.0f : 0.0f;                              \
        A.x = fmaf(v_.x, mk_, A.x);                                           \
        A.y = fmaf(v_.y, mk_, A.y);                                           \
        A.z = fmaf(v_.z, mk_, A.z);                                           \
        A.w = fmaf(v_.w, mk_, A.w);                                           \
        if (s_ > -4 && s_ < 0) {                /* straddle: 1 lane per (b,e) */\
            A.w += rowbase[(P) + 3 - off];      /* s_>=-3 => +3 valid */      \
            if (s_ >= -2) A.z += rowbase[(P) + 2 - off];                      \
            if (s_ >= -1) A.y += rowbase[(P) + 1 - off];                      \
        }                                                                     \
    }

__global__ __launch_bounds__(BLK) void gather_sum_max(
    const float* __restrict__ events, const int* __restrict__ indices,
    float* __restrict__ out, float* __restrict__ pmax)
{
    const int b  = blockIdx.y;
    const int cx = blockIdx.x;
    const int t  = (int)threadIdx.x;

    // Reflection pairing (R7): fwd chunk [cx*1024,+1024) + mirror chunk
    // [S-1024*(cx+1),+1024) -> expected gather volume ~constant in cx.
    const int pA = cx * HALF + 4 * t;
    const int pB = (S_ - HALF * (cx + 1)) + 4 * t;

    float4 accA = {0.f, 0.f, 0.f, 0.f};
    float4 accB = {0.f, 0.f, 0.f, 0.f};

    const float* evb  = events + (size_t)b * (E_ * S_);
    const int*   idxb = indices + b * E_;

#pragma unroll 4
    for (int e = 0; e < E_; ++e) {
        const int off = idxb[e];                  // block-uniform scalar load
        const float* rowbase = evb + e * S_;      // events[b,e,0]
        GATHER(accA, pA)
        GATHER(accB, pB)
    }

    // aligned float4 stores of the raw sums
    float* ob = out + (size_t)b * S_;
    *reinterpret_cast<float4*>(ob + pA) = accA;
    *reinterpret_cast<float4*>(ob + pB) = accB;

    // thread-local max of the 8 values
    float m = fmaxf(fmaxf(fmaxf(accA.x, accA.y), fmaxf(accA.z, accA.w)),
                    fmaxf(fmaxf(accB.x, accB.y), fmaxf(accB.z, accB.w)));

    // 64-lane butterfly reduce
#pragma unroll
    for (int d = 1; d < 64; d <<= 1)
        m = fmaxf(m, __shfl_xor(m, d, 64));

    __shared__ float wmax[BLK / 64];
    if ((t & 63) == 0) wmax[t >> 6] = m;
    __syncthreads();
    if (t == 0) {
        float mm = fmaxf(fmaxf(wmax[0], wmax[1]), fmaxf(wmax[2], wmax[3]));
        pmax[b * NCH + cx] = mm;   // unique slot: no memset, no atomics
    }
}

__global__ __launch_bounds__(256) void normalize_k(
    float* __restrict__ out, const float* __restrict__ pmax)
{
    const int b = blockIdx.y;
    // redundant per-block reduce of the 16 partial maxes (L2/L3-hot)
    const float* pm = pmax + b * NCH;
    float m = pm[0];
#pragma unroll
    for (int c = 1; c < NCH; ++c) m = fmaxf(m, pm[c]);
    const float inv = 1.0f / (m + 1e-8f);

    // 2 float4s per thread; row = 8192 float4s; grid.x = 16 blocks/row
    const int i0 = blockIdx.x * 512 + (int)threadIdx.x;
    const f4v* in4 = reinterpret_cast<const f4v*>(out + (size_t)b * S_);
    f4v*       o4  = reinterpret_cast<f4v*>(out + (size_t)b * S_);

    f4v v = in4[i0];
    v.x *= inv; v.y *= inv; v.z *= inv; v.w *= inv;
    __builtin_nontemporal_store(v, o4 + i0);        // out is never re-read

    f4v w = in4[i0 + 256];
    w.x *= inv; w.y *= inv; w.z *= inv; w.w *= inv;
    __builtin_nontemporal_store(w, o4 + i0 + 256);
}

extern "C" void kernel_launch(void* const* d_in, const int* in_sizes, int n_in,
                              void* d_out, int out_size, void* d_ws, size_t ws_size,
                              hipStream_t stream) {
    const float* events  = (const float*)d_in[0];
    const int*   indices = (const int*)d_in[1];
    float* out  = (float*)d_out;
    float* pmax = (float*)d_ws;          // B_*NCH floats = 8 KB, fully rewritten
                                         // by kernel A every call

    dim3 gridA(NCH, B_);                 // 16 x 128 = 2048 blocks
    gather_sum_max<<<gridA, BLK, 0, stream>>>(events, indices, out, pmax);

    dim3 gridB(16, B_);                  // 16 x 128 = 2048 blocks
    normalize_k<<<gridB, 256, 0, stream>>>(out, pmax);
}